// Round 3
// baseline (122.152 us; speedup 1.0000x reference)
//
#include <hip/hip_runtime.h>
#include <math.h>

#define BB 4
#define CI 64
#define CO 64
#define HH 96
#define WW 96
#define HW (HH*WW)      // 9216
#define K2 9
#define NT (HW/64)      // 144 tiles per batch
#define PADC 1

typedef __attribute__((ext_vector_type(8))) short short8;
typedef __attribute__((ext_vector_type(4))) float float4v;

// ws layout:
//   xT  : BB*HW*64 ushort  (pixel-major bf16 x)
//   Wf  : 18*64*32 ushort  (MFMA A-frag packed main weights)
//   MWf : 18*16*32 ushort  (MFMA A-frag packed mask weights, rows 9..15 = 0)
#define XT_USHORTS ((size_t)BB*HW*64)
#define WF_USHORTS (18*64*32)
#define MWF_USHORTS (18*16*32)

__device__ __forceinline__ float bf2f(short s) {
    return __uint_as_float(((unsigned int)(unsigned short)s) << 16);
}
__device__ __forceinline__ short f2bf(float f) {
    unsigned int u = __float_as_uint(f);
    u = (u + 0x7fffu + ((u >> 16) & 1u)) >> 16;   // RNE
    return (short)u;
}

// XCD-locality swizzle: hardware dispatches round-robin across 8 XCDs
// (xcd ~= bid % 8). Map so XCD g only gets tiles of batch g&3 -> each XCD's
// 4MB L2 caches one batch's 1.18MB xT. Bijection on [0,576).
__device__ __forceinline__ void unswz(int bid, int* b, int* tile) {
    int g = bid & 7, r = bid >> 3;      // r in 0..71
    *b = g & 3;
    *tile = (g >> 2) * 72 + r;
}

// ---------------- prep 1: x[b][c][hw] fp32 -> xT[b][p][c] bf16 ----------------
__global__ __launch_bounds__(256) void xt_kernel(const float* __restrict__ x,
                                                 unsigned short* __restrict__ xT) {
    __shared__ unsigned short ts[64][72];   // 72 pad: rows stay 16B-aligned
    int t = threadIdx.x;
    int b, tl; unswz(blockIdx.x, &b, &tl);
    int p0 = tl * 64;
    const float* xb = x + (size_t)b * CI * HW + p0;
    int pq = t & 15, cg = t >> 4;
    #pragma unroll
    for (int i = 0; i < 4; i++) {
        int c = cg + i * 16;
        float4v v = *(const float4v*)(xb + (size_t)c * HW + pq * 4);
        ts[pq * 4 + 0][c] = (unsigned short)f2bf(v[0]);
        ts[pq * 4 + 1][c] = (unsigned short)f2bf(v[1]);
        ts[pq * 4 + 2][c] = (unsigned short)f2bf(v[2]);
        ts[pq * 4 + 3][c] = (unsigned short)f2bf(v[3]);
    }
    __syncthreads();
    int px = t >> 2, cq = t & 3;
    unsigned short* xo = xT + ((size_t)b * HW + p0 + px) * 64 + cq * 16;
    short8 v0 = *(const short8*)&ts[px][cq * 16];
    short8 v1 = *(const short8*)&ts[px][cq * 16 + 8];
    *(short8*)xo = v0;
    *(short8*)(xo + 8) = v1;
}

// ---------------- prep 2: pack Wf + MWf into A-frag order ----------------
__global__ __launch_bounds__(256) void pack_kernel(const float* __restrict__ wgt,
                                                   const float* __restrict__ mw,
                                                   unsigned short* __restrict__ Wf,
                                                   unsigned short* __restrict__ MWf) {
    int i = blockIdx.x * 256 + threadIdx.x;
    if (i < WF_USHORTS) {
        int frag = i >> 11;
        int o = (i >> 5) & 63;
        int tt = i & 31;
        int k = frag >> 1, cc = frag & 1;
        int c = cc * 32 + tt;
        Wf[i] = (unsigned short)f2bf(wgt[o * 576 + c * 9 + k]);
    } else if (i < WF_USHORTS + MWF_USHORTS) {
        int e = i - WF_USHORTS;
        int frag = e >> 9;
        int m = (e >> 5) & 15;
        int tt = e & 31;
        int q = frag >> 1, cc = frag & 1;
        int c = cc * 32 + tt;
        MWf[e] = (m < 9) ? (unsigned short)f2bf(mw[m * 576 + c * 9 + q]) : 0;
    }
}

// ---------------- fused: mask conv (MFMA) + deform sample + GEMM (MFMA) -------
__global__ __launch_bounds__(256) void fused_kernel(const float* __restrict__ off,
                                                    const float* __restrict__ mbias,
                                                    const unsigned short* __restrict__ xT,
                                                    const unsigned short* __restrict__ Wf,
                                                    const unsigned short* __restrict__ MWf,
                                                    float* __restrict__ out) {
    __shared__ float s_mask[K2][64];
    __shared__ int   s_idx[K2][4][64];
    __shared__ float s_w[K2][4][64];

    int t = threadIdx.x;
    int lane = t & 63, wv = t >> 6;
    int n = lane & 15, quad = lane >> 4;
    int b, tl; unswz(blockIdx.x, &b, &tl);
    int p0 = tl * 64;
    int pxl = wv * 16 + n;
    int p = p0 + pxl;
    int h = p / WW, wc = p % WW;
    const unsigned short* xTb = xT + (size_t)b * HW * 64;

    // ---- phase A: mask conv via MFMA (rows 0..8 of a 16-row A) ----
    {
        float4v acc = {0.f, 0.f, 0.f, 0.f};
        #pragma unroll
        for (int q = 0; q < 9; q++) {
            int hh = h + q / 3 - 1, ww2 = wc + q % 3 - 1;
            bool valid = (hh >= 0) && (hh < HH) && (ww2 >= 0) && (ww2 < WW);
            int nidx = valid ? (hh * WW + ww2) : 0;
            const unsigned short* src = xTb + (size_t)nidx * 64 + quad * 8;
            #pragma unroll
            for (int cc = 0; cc < 2; cc++) {
                short8 bfrag = {0, 0, 0, 0, 0, 0, 0, 0};
                if (valid) bfrag = *(const short8*)(src + cc * 32);
                short8 afrag = *(const short8*)(MWf + ((size_t)((q * 2 + cc) * 16 + n)) * 32 + quad * 8);
                acc = __builtin_amdgcn_mfma_f32_16x16x32_bf16(afrag, bfrag, acc, 0, 0, 0);
            }
        }
        #pragma unroll
        for (int r = 0; r < 4; r++) {
            int row = quad * 4 + r;
            if (row < 9) {
                float s = acc[r] + mbias[row];
                s_mask[row][pxl] = 1.f / (1.f + expf(-s));
            }
        }
    }
    __syncthreads();

    // ---- phase B: sampling metadata (idx + mask-folded bilinear weights) ----
    for (int e = t; e < K2 * 64; e += 256) {
        int k = e >> 6, pe = e & 63;
        int pp = p0 + pe;
        int hh0 = pp / WW, ww0 = pp % WW;
        int ky = k / 3, kx = k % 3;
        float oy = off[((size_t)b * 2 * K2 + 2 * k) * HW + pp];
        float ox = off[((size_t)b * 2 * K2 + 2 * k + 1) * HW + pp];
        float m = s_mask[k][pe];
        float py = (float)(hh0 - PADC + ky) + oy;
        float pxf = (float)(ww0 - PADC + kx) + ox;
        float y0f = floorf(py), x0f = floorf(pxf);
        float wy = py - y0f, wx = pxf - x0f;
        int y0 = (int)y0f, x0 = (int)x0f;
        int y1 = y0 + 1, x1 = x0 + 1;
        int y0c = min(max(y0, 0), HH - 1), y1c = min(max(y1, 0), HH - 1);
        int x0c = min(max(x0, 0), WW - 1), x1c = min(max(x1, 0), WW - 1);
        bool vy0 = (y0 >= 0) && (y0 < HH), vy1 = (y1 >= 0) && (y1 < HH);
        bool vx0 = (x0 >= 0) && (x0 < WW), vx1 = (x1 >= 0) && (x1 < WW);
        float w00 = (1.f - wy) * (1.f - wx) * m; if (!(vy0 && vx0)) w00 = 0.f;
        float w01 = (1.f - wy) * wx * m;         if (!(vy0 && vx1)) w01 = 0.f;
        float w10 = wy * (1.f - wx) * m;         if (!(vy1 && vx0)) w10 = 0.f;
        float w11 = wy * wx * m;                 if (!(vy1 && vx1)) w11 = 0.f;
        s_idx[k][0][pe] = y0c * WW + x0c;
        s_idx[k][1][pe] = y0c * WW + x1c;
        s_idx[k][2][pe] = y1c * WW + x0c;
        s_idx[k][3][pe] = y1c * WW + x1c;
        s_w[k][0][pe] = w00; s_w[k][1][pe] = w01;
        s_w[k][2][pe] = w10; s_w[k][3][pe] = w11;
    }
    __syncthreads();

    // ---- phase C: depth-2 software-pipelined sample + MFMA GEMM ----
    float4v acc0 = {0.f, 0.f, 0.f, 0.f};
    float4v acc1 = {0.f, 0.f, 0.f, 0.f};
    float4v acc2 = {0.f, 0.f, 0.f, 0.f};
    float4v acc3 = {0.f, 0.f, 0.f, 0.f};

    const unsigned short* xq = xTb + quad * 8;
    short8 st[2][8];

    auto loadK = [&](int k, short8* dst) {
        int i0 = s_idx[k][0][pxl], i1 = s_idx[k][1][pxl];
        int i2 = s_idx[k][2][pxl], i3 = s_idx[k][3][pxl];
        dst[0] = *(const short8*)(xq + (size_t)i0 * 64);
        dst[1] = *(const short8*)(xq + (size_t)i0 * 64 + 32);
        dst[2] = *(const short8*)(xq + (size_t)i1 * 64);
        dst[3] = *(const short8*)(xq + (size_t)i1 * 64 + 32);
        dst[4] = *(const short8*)(xq + (size_t)i2 * 64);
        dst[5] = *(const short8*)(xq + (size_t)i2 * 64 + 32);
        dst[6] = *(const short8*)(xq + (size_t)i3 * 64);
        dst[7] = *(const short8*)(xq + (size_t)i3 * 64 + 32);
    };

    loadK(0, st[0]);
    loadK(1, st[1]);

    #pragma unroll
    for (int k = 0; k < 9; k++) {
        float w0 = s_w[k][0][pxl], w1 = s_w[k][1][pxl];
        float w2 = s_w[k][2][pxl], w3 = s_w[k][3][pxl];
        short8 cur[8];
        #pragma unroll
        for (int j = 0; j < 8; j++) cur[j] = st[k & 1][j];
        if (k + 2 < 9) loadK(k + 2, st[k & 1]);   // prefetch 2 taps ahead
        #pragma unroll
        for (int cc = 0; cc < 2; cc++) {
            short8 bfrag;
            #pragma unroll
            for (int j = 0; j < 8; j++) {
                float v = bf2f(cur[cc][j])     * w0 + bf2f(cur[2 + cc][j]) * w1 +
                          bf2f(cur[4 + cc][j]) * w2 + bf2f(cur[6 + cc][j]) * w3;
                bfrag[j] = f2bf(v);
            }
            const unsigned short* wp = Wf + (size_t)((k * 2 + cc) * 64) * 32 + quad * 8;
            short8 a0 = *(const short8*)(wp + (0 * 16 + n) * 32);
            short8 a1 = *(const short8*)(wp + (1 * 16 + n) * 32);
            short8 a2 = *(const short8*)(wp + (2 * 16 + n) * 32);
            short8 a3 = *(const short8*)(wp + (3 * 16 + n) * 32);
            acc0 = __builtin_amdgcn_mfma_f32_16x16x32_bf16(a0, bfrag, acc0, 0, 0, 0);
            acc1 = __builtin_amdgcn_mfma_f32_16x16x32_bf16(a1, bfrag, acc1, 0, 0, 0);
            acc2 = __builtin_amdgcn_mfma_f32_16x16x32_bf16(a2, bfrag, acc2, 0, 0, 0);
            acc3 = __builtin_amdgcn_mfma_f32_16x16x32_bf16(a3, bfrag, acc3, 0, 0, 0);
        }
    }

    // ---- epilogue: D layout col=lane&15 (px), row=quad*4+reg (o in strip) ----
    float* ob = out + (size_t)b * CO * HW + p0 + pxl;
    #pragma unroll
    for (int r = 0; r < 4; r++) {
        ob[(size_t)(0 * 16 + quad * 4 + r) * HW] = acc0[r];
        ob[(size_t)(1 * 16 + quad * 4 + r) * HW] = acc1[r];
        ob[(size_t)(2 * 16 + quad * 4 + r) * HW] = acc2[r];
        ob[(size_t)(3 * 16 + quad * 4 + r) * HW] = acc3[r];
    }
}

extern "C" void kernel_launch(void* const* d_in, const int* in_sizes, int n_in,
                              void* d_out, int out_size, void* d_ws, size_t ws_size,
                              hipStream_t stream) {
    const float* x   = (const float*)d_in[0];
    const float* off = (const float*)d_in[1];
    const float* wgt = (const float*)d_in[2];
    const float* mw  = (const float*)d_in[3];
    const float* mb  = (const float*)d_in[4];
    float* out = (float*)d_out;

    unsigned short* xT  = (unsigned short*)d_ws;
    unsigned short* Wf  = xT + XT_USHORTS;
    unsigned short* MWf = Wf + WF_USHORTS;

    hipLaunchKernelGGL(xt_kernel, dim3(BB * NT), dim3(256), 0, stream, x, xT);
    hipLaunchKernelGGL(pack_kernel, dim3((WF_USHORTS + MWF_USHORTS + 255) / 256), dim3(256),
                       0, stream, wgt, mw, Wf, MWf);
    hipLaunchKernelGGL(fused_kernel, dim3(BB * NT), dim3(256), 0, stream,
                       off, mb, xT, Wf, MWf, out);
}

// Round 4
// 112.123 us; speedup vs baseline: 1.0894x; 1.0894x over previous
//
#include <hip/hip_runtime.h>
#include <math.h>

#define BB 4
#define CI 64
#define CO 64
#define HH 96
#define WW 96
#define HW (HH*WW)      // 9216
#define K2 9
#define NT (HW/64)      // 144 64-px tiles per batch (prep)
#define TPX 32          // px per fused block
#define NTT (HW/TPX)    // 288 32-px tiles per batch (fused)
#define PADC 1

typedef __attribute__((ext_vector_type(8))) short short8;
typedef __attribute__((ext_vector_type(4))) float float4v;

// ws layout:
//   xT  : BB*HW*64 ushort  (pixel-major bf16 x)
//   Wf  : 18*64*32 ushort  (MFMA A-frag packed main weights)
//   MWf : 18*16*32 ushort  (MFMA A-frag packed mask weights, rows 9..15 = 0)
#define XT_USHORTS ((size_t)BB*HW*64)
#define WF_USHORTS (18*64*32)
#define MWF_USHORTS (18*16*32)

__device__ __forceinline__ float bf2f(short s) {
    return __uint_as_float(((unsigned int)(unsigned short)s) << 16);
}
__device__ __forceinline__ short f2bf(float f) {
    unsigned int u = __float_as_uint(f);
    u = (u + 0x7fffu + ((u >> 16) & 1u)) >> 16;   // RNE
    return (short)u;
}

// XCD swizzle (hw dispatch ~ bid%8 -> XCD): XCD g serves only batch g&3 so its
// 4MB L2 caches that batch's 1.18MB xT. Bijection verified. [R2: FETCH 15->4MB]
__device__ __forceinline__ void unswz64(int bid, int* b, int* tile) {
    int g = bid & 7, r = bid >> 3;      // r in 0..71
    *b = g & 3;
    *tile = (g >> 2) * 72 + r;          // [0,144)
}
__device__ __forceinline__ void unswz32(int bid, int* b, int* tile) {
    int g = bid & 7, r = bid >> 3;      // r in 0..143
    *b = g & 3;
    *tile = (g >> 2) * 144 + r;         // [0,288)
}

// ---------------- prep: x transpose->bf16 (576 blocks) + weight pack (360) ----
__global__ __launch_bounds__(256) void prep_kernel(const float* __restrict__ x,
                                                   const float* __restrict__ wgt,
                                                   const float* __restrict__ mw,
                                                   unsigned short* __restrict__ xT,
                                                   unsigned short* __restrict__ Wf,
                                                   unsigned short* __restrict__ MWf) {
    __shared__ unsigned short ts[64][72];
    int t = threadIdx.x;
    if (blockIdx.x < BB * NT) {
        int b, tl; unswz64(blockIdx.x, &b, &tl);
        int p0 = tl * 64;
        const float* xb = x + (size_t)b * CI * HW + p0;
        int pq = t & 15, cg = t >> 4;
        #pragma unroll
        for (int i = 0; i < 4; i++) {
            int c = cg + i * 16;
            float4v v = *(const float4v*)(xb + (size_t)c * HW + pq * 4);
            ts[pq * 4 + 0][c] = (unsigned short)f2bf(v[0]);
            ts[pq * 4 + 1][c] = (unsigned short)f2bf(v[1]);
            ts[pq * 4 + 2][c] = (unsigned short)f2bf(v[2]);
            ts[pq * 4 + 3][c] = (unsigned short)f2bf(v[3]);
        }
        __syncthreads();
        int px = t >> 2, cq = t & 3;
        unsigned short* xo = xT + ((size_t)b * HW + p0 + px) * 64 + cq * 16;
        *(short8*)xo       = *(const short8*)&ts[px][cq * 16];
        *(short8*)(xo + 8) = *(const short8*)&ts[px][cq * 16 + 8];
    } else {
        int i = (blockIdx.x - BB * NT) * 256 + t;
        if (i < WF_USHORTS) {
            int frag = i >> 11;
            int o = (i >> 5) & 63;
            int tt = i & 31;
            int k = frag >> 1, cc = frag & 1;
            int c = cc * 32 + tt;
            Wf[i] = (unsigned short)f2bf(wgt[o * 576 + c * 9 + k]);
        } else if (i < WF_USHORTS + MWF_USHORTS) {
            int e = i - WF_USHORTS;
            int frag = e >> 9;
            int m = (e >> 5) & 15;
            int tt = e & 31;
            int q = frag >> 1, cc = frag & 1;
            int c = cc * 32 + tt;
            MWf[e] = (m < 9) ? (unsigned short)f2bf(mw[m * 576 + c * 9 + q]) : 0;
        }
    }
}

// ---------------- fused: mask conv + deform sample + GEMM --------------------
// Block = 256 threads = 4 waves: wave (pg, ch) = (wv&1 px-group, wv>>1 c-half).
// Each wave: 16 px, 32 input channels. Cross-wave c-reduce via LDS.
__global__ __launch_bounds__(256) void fused_kernel(const float* __restrict__ off,
                                                    const float* __restrict__ mbias,
                                                    const unsigned short* __restrict__ xT,
                                                    const unsigned short* __restrict__ Wf,
                                                    const unsigned short* __restrict__ MWf,
                                                    float* __restrict__ out) {
    __shared__ float s_mred[2][K2][TPX];
    __shared__ int   s_idx[K2][4][TPX];
    __shared__ float s_w[K2][4][TPX];
    __shared__ float s_part[2][16][64];   // [pg][o-frag j][lane] lane-contig: no conflicts

    int t = threadIdx.x;
    int lane = t & 63, wv = t >> 6;
    int pg = wv & 1, ch = wv >> 1;
    int n = lane & 15, quad = lane >> 4;
    int b, tl; unswz32(blockIdx.x, &b, &tl);
    int p0 = tl * TPX;
    int pxl = pg * 16 + n;                 // px within tile
    int p = p0 + pxl;
    int h = p / WW, wc = p % WW;
    const unsigned short* xTb = xT + (size_t)b * HW * 64;
    int cbase = ch * 32 + quad * 8;        // this lane's channel offset

    // ---- phase A: mask-conv partials via MFMA (this wave's 32 channels) ----
    {
        float4v macc = {0.f, 0.f, 0.f, 0.f};
        #pragma unroll
        for (int q = 0; q < 9; q++) {
            int hh = h + q / 3 - 1, ww2 = wc + q % 3 - 1;
            bool valid = (hh >= 0) && (hh < HH) && (ww2 >= 0) && (ww2 < WW);
            int nidx = valid ? (hh * WW + ww2) : 0;
            short8 bfrag = {0, 0, 0, 0, 0, 0, 0, 0};
            if (valid) bfrag = *(const short8*)(xTb + (size_t)nidx * 64 + cbase);
            short8 afrag = *(const short8*)(MWf + ((size_t)((q * 2 + ch) * 16 + n)) * 32 + quad * 8);
            macc = __builtin_amdgcn_mfma_f32_16x16x32_bf16(afrag, bfrag, macc, 0, 0, 0);
        }
        #pragma unroll
        for (int r = 0; r < 4; r++) {
            int row = quad * 4 + r;
            if (row < 9) s_mred[ch][row][pxl] = macc[r];
        }
    }
    __syncthreads();

    // ---- phase B: sampling metadata, mask folded into bilinear weights ----
    for (int e = t; e < K2 * TPX; e += 256) {
        int k = e >> 5, pe = e & 31;
        int pp = p0 + pe;
        int hh0 = pp / WW, ww0 = pp % WW;
        int ky = k / 3, kx = k % 3;
        float oy = off[((size_t)b * 2 * K2 + 2 * k) * HW + pp];
        float ox = off[((size_t)b * 2 * K2 + 2 * k + 1) * HW + pp];
        float s = s_mred[0][k][pe] + s_mred[1][k][pe] + mbias[k];
        float m = 1.f / (1.f + expf(-s));
        float py = (float)(hh0 - PADC + ky) + oy;
        float pxf = (float)(ww0 - PADC + kx) + ox;
        float y0f = floorf(py), x0f = floorf(pxf);
        float wy = py - y0f, wx = pxf - x0f;
        int y0 = (int)y0f, x0 = (int)x0f;
        int y1 = y0 + 1, x1 = x0 + 1;
        int y0c = min(max(y0, 0), HH - 1), y1c = min(max(y1, 0), HH - 1);
        int x0c = min(max(x0, 0), WW - 1), x1c = min(max(x1, 0), WW - 1);
        bool vy0 = (y0 >= 0) && (y0 < HH), vy1 = (y1 >= 0) && (y1 < HH);
        bool vx0 = (x0 >= 0) && (x0 < WW), vx1 = (x1 >= 0) && (x1 < WW);
        float w00 = (1.f - wy) * (1.f - wx) * m; if (!(vy0 && vx0)) w00 = 0.f;
        float w01 = (1.f - wy) * wx * m;         if (!(vy0 && vx1)) w01 = 0.f;
        float w10 = wy * (1.f - wx) * m;         if (!(vy1 && vx0)) w10 = 0.f;
        float w11 = wy * wx * m;                 if (!(vy1 && vx1)) w11 = 0.f;
        s_idx[k][0][pe] = y0c * WW + x0c;
        s_idx[k][1][pe] = y0c * WW + x1c;
        s_idx[k][2][pe] = y1c * WW + x0c;
        s_idx[k][3][pe] = y1c * WW + x1c;
        s_w[k][0][pe] = w00; s_w[k][1][pe] = w01;
        s_w[k][2][pe] = w10; s_w[k][3][pe] = w11;
    }
    __syncthreads();

    // ---- phase C: sample (register B-frags) + MFMA over this wave's 32 ch ----
    float4v acc0 = {0.f, 0.f, 0.f, 0.f};
    float4v acc1 = {0.f, 0.f, 0.f, 0.f};
    float4v acc2 = {0.f, 0.f, 0.f, 0.f};
    float4v acc3 = {0.f, 0.f, 0.f, 0.f};
    const unsigned short* xq = xTb + cbase;

    #pragma unroll
    for (int k = 0; k < 9; k++) {
        int i0 = s_idx[k][0][pxl], i1 = s_idx[k][1][pxl];
        int i2 = s_idx[k][2][pxl], i3 = s_idx[k][3][pxl];
        float w0 = s_w[k][0][pxl], w1 = s_w[k][1][pxl];
        float w2 = s_w[k][2][pxl], w3 = s_w[k][3][pxl];
        short8 u0 = *(const short8*)(xq + (size_t)i0 * 64);
        short8 u1 = *(const short8*)(xq + (size_t)i1 * 64);
        short8 u2 = *(const short8*)(xq + (size_t)i2 * 64);
        short8 u3 = *(const short8*)(xq + (size_t)i3 * 64);
        short8 bfrag;
        #pragma unroll
        for (int j = 0; j < 8; j++) {
            float v = bf2f(u0[j]) * w0 + bf2f(u1[j]) * w1 +
                      bf2f(u2[j]) * w2 + bf2f(u3[j]) * w3;
            bfrag[j] = f2bf(v);
        }
        const unsigned short* wp = Wf + (size_t)((k * 2 + ch) * 64) * 32 + quad * 8;
        short8 a0 = *(const short8*)(wp + (0 * 16 + n) * 32);
        short8 a1 = *(const short8*)(wp + (1 * 16 + n) * 32);
        short8 a2 = *(const short8*)(wp + (2 * 16 + n) * 32);
        short8 a3 = *(const short8*)(wp + (3 * 16 + n) * 32);
        acc0 = __builtin_amdgcn_mfma_f32_16x16x32_bf16(a0, bfrag, acc0, 0, 0, 0);
        acc1 = __builtin_amdgcn_mfma_f32_16x16x32_bf16(a1, bfrag, acc1, 0, 0, 0);
        acc2 = __builtin_amdgcn_mfma_f32_16x16x32_bf16(a2, bfrag, acc2, 0, 0, 0);
        acc3 = __builtin_amdgcn_mfma_f32_16x16x32_bf16(a3, bfrag, acc3, 0, 0, 0);
    }

    // ---- cross-wave c-reduce + epilogue ----
    if (ch == 1) {
        #pragma unroll
        for (int r = 0; r < 4; r++) {
            s_part[pg][0 * 4 + r][lane] = acc0[r];
            s_part[pg][1 * 4 + r][lane] = acc1[r];
            s_part[pg][2 * 4 + r][lane] = acc2[r];
            s_part[pg][3 * 4 + r][lane] = acc3[r];
        }
    }
    __syncthreads();
    if (ch == 0) {
        float* ob = out + (size_t)b * CO * HW + p0 + pxl;
        #pragma unroll
        for (int r = 0; r < 4; r++) {
            ob[(size_t)(0 * 16 + quad * 4 + r) * HW] = acc0[r] + s_part[pg][0 * 4 + r][lane];
            ob[(size_t)(1 * 16 + quad * 4 + r) * HW] = acc1[r] + s_part[pg][1 * 4 + r][lane];
            ob[(size_t)(2 * 16 + quad * 4 + r) * HW] = acc2[r] + s_part[pg][2 * 4 + r][lane];
            ob[(size_t)(3 * 16 + quad * 4 + r) * HW] = acc3[r] + s_part[pg][3 * 4 + r][lane];
        }
    }
}

extern "C" void kernel_launch(void* const* d_in, const int* in_sizes, int n_in,
                              void* d_out, int out_size, void* d_ws, size_t ws_size,
                              hipStream_t stream) {
    const float* x   = (const float*)d_in[0];
    const float* off = (const float*)d_in[1];
    const float* wgt = (const float*)d_in[2];
    const float* mw  = (const float*)d_in[3];
    const float* mb  = (const float*)d_in[4];
    float* out = (float*)d_out;

    unsigned short* xT  = (unsigned short*)d_ws;
    unsigned short* Wf  = xT + XT_USHORTS;
    unsigned short* MWf = Wf + WF_USHORTS;

    int prep_grid = BB * NT + (WF_USHORTS + MWF_USHORTS + 255) / 256;   // 576 + 360
    hipLaunchKernelGGL(prep_kernel, dim3(prep_grid), dim3(256), 0, stream,
                       x, wgt, mw, xT, Wf, MWf);
    hipLaunchKernelGGL(fused_kernel, dim3(BB * NTT), dim3(256), 0, stream,
                       off, mb, xT, Wf, MWf, out);
}

// Round 5
// 106.768 us; speedup vs baseline: 1.1441x; 1.0502x over previous
//
#include <hip/hip_runtime.h>
#include <math.h>

#define BB 4
#define CI 64
#define CO 64
#define HH 96
#define WW 96
#define HW (HH*WW)      // 9216
#define K2 9
#define TPX 16          // px per fused block
#define NTT (HW/TPX)    // 576 tiles per batch (fused)
#define NTP 288         // 32-px tiles per batch (prep)
#define PADC 1

typedef __attribute__((ext_vector_type(8))) short short8;
typedef __attribute__((ext_vector_type(4))) float float4v;

// ws layout:
//   xT  : BB*HW*64 ushort  (pixel-major bf16 x)
//   Wf  : 18*64*32 ushort  (MFMA A-frag packed main weights)
//   MWf : 18*16*32 ushort  (MFMA A-frag packed mask weights, rows 9..15 = 0)
#define XT_USHORTS ((size_t)BB*HW*64)
#define WF_USHORTS (18*64*32)
#define MWF_USHORTS (18*16*32)

__device__ __forceinline__ float bf2f(short s) {
    return __uint_as_float(((unsigned int)(unsigned short)s) << 16);
}
__device__ __forceinline__ short f2bf(float f) {
    unsigned int u = __float_as_uint(f);
    u = (u + 0x7fffu + ((u >> 16) & 1u)) >> 16;   // RNE
    return (short)u;
}

// XCD swizzle (hw dispatch ~ bid%8 -> XCD): XCD g serves only batch g&3 so its
// 4MB L2 caches that batch's 1.18MB xT. [R3: FETCH 15->4MB verified]
__device__ __forceinline__ void unswz16(int bid, int* b, int* tile) {
    int g = bid & 7, r = bid >> 3;      // r in 0..287
    *b = g & 3;
    *tile = (g >> 2) * 288 + r;         // [0,576)
}
__device__ __forceinline__ void unswz32(int bid, int* b, int* tile) {
    int g = bid & 7, r = bid >> 3;      // r in 0..143
    *b = g & 3;
    *tile = (g >> 2) * 144 + r;         // [0,288)
}

// ---------------- prep: x transpose->bf16 (1152 blocks) + weight pack (360) ---
#define PBASE (BB*NTP)   // 1152
__global__ __launch_bounds__(256) void prep_kernel(const float* __restrict__ x,
                                                   const float* __restrict__ wgt,
                                                   const float* __restrict__ mw,
                                                   unsigned short* __restrict__ xT,
                                                   unsigned short* __restrict__ Wf,
                                                   unsigned short* __restrict__ MWf) {
    __shared__ unsigned short ts[32][72];
    int t = threadIdx.x;
    if (blockIdx.x < PBASE) {
        int b, tl; unswz32(blockIdx.x, &b, &tl);
        int p0 = tl * 32;
        const float* xb = x + (size_t)b * CI * HW + p0;
        int c0 = t >> 3, pq = t & 7;
        #pragma unroll
        for (int i = 0; i < 2; i++) {
            int c = c0 + i * 32;
            float4v v = *(const float4v*)(xb + (size_t)c * HW + pq * 4);
            ts[pq * 4 + 0][c] = (unsigned short)f2bf(v[0]);
            ts[pq * 4 + 1][c] = (unsigned short)f2bf(v[1]);
            ts[pq * 4 + 2][c] = (unsigned short)f2bf(v[2]);
            ts[pq * 4 + 3][c] = (unsigned short)f2bf(v[3]);
        }
        __syncthreads();
        int px = t >> 3, cq = t & 7;
        unsigned short* xo = xT + ((size_t)b * HW + p0 + px) * 64 + cq * 8;
        *(short8*)xo = *(const short8*)&ts[px][cq * 8];
    } else {
        int i = (blockIdx.x - PBASE) * 256 + t;
        if (i < WF_USHORTS) {
            int frag = i >> 11;
            int o = (i >> 5) & 63;
            int tt = i & 31;
            int k = frag >> 1, cc = frag & 1;
            int c = cc * 32 + tt;
            Wf[i] = (unsigned short)f2bf(wgt[o * 576 + c * 9 + k]);
        } else if (i < WF_USHORTS + MWF_USHORTS) {
            int e = i - WF_USHORTS;
            int frag = e >> 9;
            int m = (e >> 5) & 15;
            int tt = e & 31;
            int q = frag >> 1, cc = frag & 1;
            int c = cc * 32 + tt;
            MWf[e] = (m < 9) ? (unsigned short)f2bf(mw[m * 576 + c * 9 + q]) : 0;
        }
    }
}

// ---------------- fused: mask conv + deform sample + GEMM --------------------
// Block = 4 waves over ONE 16-px tile: wave (ch = wv&1: c-half, tg = wv>>1:
// tap-group {0..4}/{5..8}). Mask conv also 4-way split. Partials reduced in LDS.
// launch_bounds(256,6): 6 waves/SIMD target, VGPR cap ~85 leaves hoist headroom.
__global__ __launch_bounds__(256, 6) void fused_kernel(const float* __restrict__ off,
                                                       const float* __restrict__ mbias,
                                                       const unsigned short* __restrict__ xT,
                                                       const unsigned short* __restrict__ Wf,
                                                       const unsigned short* __restrict__ MWf,
                                                       float* __restrict__ out) {
    __shared__ float s_mred[2][2][K2][TPX];   // [ch][tg][tap][px]
    __shared__ int   s_idx[K2][4][TPX];
    __shared__ float s_w[K2][4][TPX];
    __shared__ float s_part[3][16][64];       // [wave-1][o-frag j][lane]

    int t = threadIdx.x;
    int lane = t & 63, wv = t >> 6;
    int ch = wv & 1, tg = wv >> 1;
    int n = lane & 15, quad = lane >> 4;
    int b, tl; unswz16(blockIdx.x, &b, &tl);
    int p0 = tl * TPX;
    int p = p0 + n;
    int h = p / WW, wc = p % WW;
    const unsigned short* xTb = xT + (size_t)b * HW * 64;
    int cbase = ch * 32 + quad * 8;

    // ---- phase A: mask-conv partials via MFMA (this wave: 32 ch x tap-group) --
    {
        float4v macc = {0.f, 0.f, 0.f, 0.f};
#define PHASE_A(QB, QE)                                                          \
        _Pragma("unroll")                                                        \
        for (int q = QB; q < QE; q++) {                                          \
            int hh = h + q / 3 - 1, ww2 = wc + q % 3 - 1;                        \
            bool valid = (hh >= 0) && (hh < HH) && (ww2 >= 0) && (ww2 < WW);     \
            int nidx = valid ? (hh * WW + ww2) : 0;                              \
            short8 bfrag = {0, 0, 0, 0, 0, 0, 0, 0};                             \
            if (valid) bfrag = *(const short8*)(xTb + (size_t)nidx * 64 + cbase);\
            short8 afrag = *(const short8*)(MWf +                                \
                ((size_t)((q * 2 + ch) * 16 + n)) * 32 + quad * 8);              \
            macc = __builtin_amdgcn_mfma_f32_16x16x32_bf16(afrag, bfrag, macc, 0, 0, 0); \
        }
        if (tg == 0) { PHASE_A(0, 5) } else { PHASE_A(5, 9) }
        #pragma unroll
        for (int r = 0; r < 4; r++) {
            int row = quad * 4 + r;
            if (row < 9) s_mred[ch][tg][row][n] = macc[r];
        }
    }
    __syncthreads();

    // ---- phase B: sampling metadata (one thread per (tap,px)) ----
    if (t < K2 * TPX) {
        int k = t >> 4, pe = t & 15;
        int pp = p0 + pe;
        int hh0 = pp / WW, ww0 = pp % WW;
        int ky = k / 3, kx = k % 3;
        float oy = off[((size_t)b * 2 * K2 + 2 * k) * HW + pp];
        float ox = off[((size_t)b * 2 * K2 + 2 * k + 1) * HW + pp];
        float s = s_mred[0][0][k][pe] + s_mred[0][1][k][pe] +
                  s_mred[1][0][k][pe] + s_mred[1][1][k][pe] + mbias[k];
        float m = 1.f / (1.f + expf(-s));
        float py = (float)(hh0 - PADC + ky) + oy;
        float pxf = (float)(ww0 - PADC + kx) + ox;
        float y0f = floorf(py), x0f = floorf(pxf);
        float wy = py - y0f, wx = pxf - x0f;
        int y0 = (int)y0f, x0 = (int)x0f;
        int y1 = y0 + 1, x1 = x0 + 1;
        int y0c = min(max(y0, 0), HH - 1), y1c = min(max(y1, 0), HH - 1);
        int x0c = min(max(x0, 0), WW - 1), x1c = min(max(x1, 0), WW - 1);
        bool vy0 = (y0 >= 0) && (y0 < HH), vy1 = (y1 >= 0) && (y1 < HH);
        bool vx0 = (x0 >= 0) && (x0 < WW), vx1 = (x1 >= 0) && (x1 < WW);
        float w00 = (1.f - wy) * (1.f - wx) * m; if (!(vy0 && vx0)) w00 = 0.f;
        float w01 = (1.f - wy) * wx * m;         if (!(vy0 && vx1)) w01 = 0.f;
        float w10 = wy * (1.f - wx) * m;         if (!(vy1 && vx0)) w10 = 0.f;
        float w11 = wy * wx * m;                 if (!(vy1 && vx1)) w11 = 0.f;
        s_idx[k][0][pe] = y0c * WW + x0c;
        s_idx[k][1][pe] = y0c * WW + x1c;
        s_idx[k][2][pe] = y1c * WW + x0c;
        s_idx[k][3][pe] = y1c * WW + x1c;
        s_w[k][0][pe] = w00; s_w[k][1][pe] = w01;
        s_w[k][2][pe] = w10; s_w[k][3][pe] = w11;
    }
    __syncthreads();

    // ---- phase C: sample + MFMA over this wave's (c-half x tap-group) ----
    float4v acc0 = {0.f, 0.f, 0.f, 0.f};
    float4v acc1 = {0.f, 0.f, 0.f, 0.f};
    float4v acc2 = {0.f, 0.f, 0.f, 0.f};
    float4v acc3 = {0.f, 0.f, 0.f, 0.f};
    const unsigned short* xq = xTb + cbase;

#define PHASE_C(KB, KE)                                                          \
    _Pragma("unroll")                                                            \
    for (int k = KB; k < KE; k++) {                                              \
        int i0 = s_idx[k][0][n], i1 = s_idx[k][1][n];                            \
        int i2 = s_idx[k][2][n], i3 = s_idx[k][3][n];                            \
        float w0 = s_w[k][0][n], w1 = s_w[k][1][n];                              \
        float w2 = s_w[k][2][n], w3 = s_w[k][3][n];                              \
        short8 u0 = *(const short8*)(xq + (size_t)i0 * 64);                      \
        short8 u1 = *(const short8*)(xq + (size_t)i1 * 64);                      \
        short8 u2 = *(const short8*)(xq + (size_t)i2 * 64);                      \
        short8 u3 = *(const short8*)(xq + (size_t)i3 * 64);                      \
        short8 bfrag;                                                            \
        _Pragma("unroll")                                                        \
        for (int j = 0; j < 8; j++) {                                            \
            float v = bf2f(u0[j]) * w0 + bf2f(u1[j]) * w1 +                      \
                      bf2f(u2[j]) * w2 + bf2f(u3[j]) * w3;                       \
            bfrag[j] = f2bf(v);                                                  \
        }                                                                        \
        const unsigned short* wp = Wf + (size_t)((k * 2 + ch) * 64) * 32 + quad * 8; \
        short8 a0 = *(const short8*)(wp + (0 * 16 + n) * 32);                    \
        short8 a1 = *(const short8*)(wp + (1 * 16 + n) * 32);                    \
        short8 a2 = *(const short8*)(wp + (2 * 16 + n) * 32);                    \
        short8 a3 = *(const short8*)(wp + (3 * 16 + n) * 32);                    \
        acc0 = __builtin_amdgcn_mfma_f32_16x16x32_bf16(a0, bfrag, acc0, 0, 0, 0);\
        acc1 = __builtin_amdgcn_mfma_f32_16x16x32_bf16(a1, bfrag, acc1, 0, 0, 0);\
        acc2 = __builtin_amdgcn_mfma_f32_16x16x32_bf16(a2, bfrag, acc2, 0, 0, 0);\
        acc3 = __builtin_amdgcn_mfma_f32_16x16x32_bf16(a3, bfrag, acc3, 0, 0, 0);\
    }
    if (tg == 0) { PHASE_C(0, 5) } else { PHASE_C(5, 9) }

    // ---- cross-wave reduce (4 partials) + epilogue ----
    if (wv != 0) {
        #pragma unroll
        for (int r = 0; r < 4; r++) {
            s_part[wv - 1][0 * 4 + r][lane] = acc0[r];
            s_part[wv - 1][1 * 4 + r][lane] = acc1[r];
            s_part[wv - 1][2 * 4 + r][lane] = acc2[r];
            s_part[wv - 1][3 * 4 + r][lane] = acc3[r];
        }
    }
    __syncthreads();
    if (wv == 0) {
        float* ob = out + (size_t)b * CO * HW + p0 + n;
        #pragma unroll
        for (int r = 0; r < 4; r++) {
            int j0 = 0 * 4 + r, j1 = 1 * 4 + r, j2 = 2 * 4 + r, j3 = 3 * 4 + r;
            ob[(size_t)(0 * 16 + quad * 4 + r) * HW] =
                acc0[r] + s_part[0][j0][lane] + s_part[1][j0][lane] + s_part[2][j0][lane];
            ob[(size_t)(1 * 16 + quad * 4 + r) * HW] =
                acc1[r] + s_part[0][j1][lane] + s_part[1][j1][lane] + s_part[2][j1][lane];
            ob[(size_t)(2 * 16 + quad * 4 + r) * HW] =
                acc2[r] + s_part[0][j2][lane] + s_part[1][j2][lane] + s_part[2][j2][lane];
            ob[(size_t)(3 * 16 + quad * 4 + r) * HW] =
                acc3[r] + s_part[0][j3][lane] + s_part[1][j3][lane] + s_part[2][j3][lane];
        }
    }
}

extern "C" void kernel_launch(void* const* d_in, const int* in_sizes, int n_in,
                              void* d_out, int out_size, void* d_ws, size_t ws_size,
                              hipStream_t stream) {
    const float* x   = (const float*)d_in[0];
    const float* off = (const float*)d_in[1];
    const float* wgt = (const float*)d_in[2];
    const float* mw  = (const float*)d_in[3];
    const float* mb  = (const float*)d_in[4];
    float* out = (float*)d_out;

    unsigned short* xT  = (unsigned short*)d_ws;
    unsigned short* Wf  = xT + XT_USHORTS;
    unsigned short* MWf = Wf + WF_USHORTS;

    int prep_grid = PBASE + (WF_USHORTS + MWF_USHORTS + 255) / 256;   // 1152 + 360
    hipLaunchKernelGGL(prep_kernel, dim3(prep_grid), dim3(256), 0, stream,
                       x, wgt, mw, xT, Wf, MWf);
    hipLaunchKernelGGL(fused_kernel, dim3(BB * NTT), dim3(256), 0, stream,
                       off, mb, xT, Wf, MWf, out);
}